// Round 1
// baseline (1564.782 us; speedup 1.0000x reference)
//
#include <hip/hip_runtime.h>
#include <hip/hip_bf16.h>
#include <cstddef>

// Problem constants
#define NN 10000
#define EE 160000
#define ETOT (EE + NN)
#define F_IN 128
#define H1 10
#define C1 128
#define HC1 (H1 * C1)   // 1280
#define H2 1
#define C2 1024
#define HC2 (H2 * C2)   // 1024
#define OUT_DIM 1024

// ---------------- CSR build ----------------
__global__ void hist_kernel(const int* __restrict__ edst, int* __restrict__ deg) {
    int e = blockIdx.x * 256 + threadIdx.x;
    if (e >= ETOT) return;
    int d = (e < EE) ? edst[e] : (e - EE);
    atomicAdd(&deg[d], 1);
}

__global__ void scan_kernel(const int* __restrict__ deg, int* __restrict__ row_start) {
    __shared__ int buf[1024];
    int carry = 0;
    for (int base = 0; base < NN; base += 1024) {
        int i = base + threadIdx.x;
        int v = (i < NN) ? deg[i] : 0;
        buf[threadIdx.x] = v;
        __syncthreads();
        for (int off = 1; off < 1024; off <<= 1) {
            int t = (threadIdx.x >= off) ? buf[threadIdx.x - off] : 0;
            __syncthreads();
            buf[threadIdx.x] += t;
            __syncthreads();
        }
        int incl = buf[threadIdx.x];
        if (i < NN) row_start[i] = carry + incl - v;   // exclusive
        carry += buf[1023];
        __syncthreads();
    }
    if (threadIdx.x == 0) row_start[NN] = carry;
}

__global__ void fill_kernel(const int* __restrict__ esrc, const int* __restrict__ edst,
                            const int* __restrict__ row_start, int* __restrict__ cursor,
                            int* __restrict__ slot_src) {
    int e = blockIdx.x * 256 + threadIdx.x;
    if (e >= ETOT) return;
    int s, d;
    if (e < EE) { s = esrc[e]; d = edst[e]; }
    else        { s = d = e - EE; }
    int pos = atomicAdd(&cursor[d], 1);
    slot_src[row_start[d] + pos] = s;
}

// ---------------- fp32 tiled GEMM: C = A[MxK] * B[KxN] (+bias, +act) ----------------
// ACT: 0 = none, 1 = relu
template<int ACT>
__global__ void gemm_f32(const float* __restrict__ A, const float* __restrict__ B,
                         const float* __restrict__ bias, float* __restrict__ C,
                         int M, int N, int K) {
    __shared__ float As[16][65];
    __shared__ float Bs[16][65];
    int bm = blockIdx.y * 64;
    int bn = blockIdx.x * 64;
    int tid = threadIdx.y * 16 + threadIdx.x;
    float acc[4][4] = {};
    for (int k0 = 0; k0 < K; k0 += 16) {
        for (int i = tid; i < 64 * 16; i += 256) {
            int m = i >> 4, k = i & 15;
            int gr = bm + m;
            As[k][m] = (gr < M) ? A[(size_t)gr * K + k0 + k] : 0.f;
        }
        for (int i = tid; i < 16 * 64; i += 256) {
            int k = i >> 6, n = i & 63;
            Bs[k][n] = B[(size_t)(k0 + k) * N + bn + n];
        }
        __syncthreads();
#pragma unroll
        for (int k = 0; k < 16; ++k) {
            float a[4], b[4];
#pragma unroll
            for (int i = 0; i < 4; i++) a[i] = As[k][threadIdx.y * 4 + i];
#pragma unroll
            for (int j = 0; j < 4; j++) b[j] = Bs[k][threadIdx.x * 4 + j];
#pragma unroll
            for (int i = 0; i < 4; i++)
#pragma unroll
                for (int j = 0; j < 4; j++) acc[i][j] += a[i] * b[j];
        }
        __syncthreads();
    }
#pragma unroll
    for (int i = 0; i < 4; i++) {
        int r = bm + threadIdx.y * 4 + i;
        if (r >= M) continue;
#pragma unroll
        for (int j = 0; j < 4; j++) {
            int cidx = bn + threadIdx.x * 4 + j;
            float v = acc[i][j];
            if (bias) v += bias[cidx];
            if (ACT == 1) v = fmaxf(v, 0.f);
            C[(size_t)r * N + cidx] = v;
        }
    }
}

// ---------------- attention logits: a_s[n,h] = sum_c h[n,h,c]*att_s[h,c] ----------------
__global__ void att_logits(const float* __restrict__ h, const float* __restrict__ att_s,
                           const float* __restrict__ att_d, float* __restrict__ a_s,
                           float* __restrict__ a_d, int H, int C) {
    int nh = blockIdx.x;
    int n = nh / H, hd = nh % H;
    int lane = threadIdx.x;
    const float* row = h + (size_t)n * H * C + (size_t)hd * C;
    float ps = 0.f, pd = 0.f;
    for (int c = lane; c < C; c += 64) {
        float v = row[c];
        ps += v * att_s[hd * C + c];
        pd += v * att_d[hd * C + c];
    }
    for (int off = 32; off; off >>= 1) {
        ps += __shfl_down(ps, off);
        pd += __shfl_down(pd, off);
    }
    if (lane == 0) {
        a_s[n * H + hd] = ps;
        a_d[n * H + hd] = pd;
    }
}

// ---------------- per-dst softmax over in-edges (CSR), write alpha by slot ----------------
__global__ void att_alpha(const int* __restrict__ row_start, const int* __restrict__ slot_src,
                          const float* __restrict__ a_s, const float* __restrict__ a_d,
                          float* __restrict__ alpha, int H) {
    int d = blockIdx.x;
    int lane = threadIdx.x;
    int s0 = row_start[d], s1 = row_start[d + 1];
    for (int hd = 0; hd < H; ++hd) {
        float ad = a_d[d * H + hd];
        float sum = 0.f;
        for (int s = s0 + lane; s < s1; s += 64) {
            float e = a_s[slot_src[s] * H + hd] + ad;
            e = (e > 0.f) ? e : 0.2f * e;          // leaky_relu 0.2
            float ex = expf(e);                     // no max-shift: |e| small by construction
            alpha[(size_t)s * H + hd] = ex;
            sum += ex;
        }
        for (int off = 32; off; off >>= 1) sum += __shfl_down(sum, off);
        sum = __shfl(sum, 0);
        float inv = 1.f / (sum + 1e-16f);
        for (int s = s0 + lane; s < s1; s += 64) alpha[(size_t)s * H + hd] *= inv;
    }
}

// ---------------- scatter: out[d,c] = act( sum_e alpha[e,h(c)] * h[src_e, c] + bias[c] ) ----
// ACT: 1 = elu, 2 = relu
template<int ACT>
__global__ void gat_scatter(const int* __restrict__ row_start, const int* __restrict__ slot_src,
                            const float* __restrict__ alpha, const float* __restrict__ h,
                            const float* __restrict__ bias, float* __restrict__ out,
                            int HC, int C, int H) {
    int d = blockIdx.x;
    int c = blockIdx.y * 256 + threadIdx.x;
    if (c >= HC) return;
    int hd = c / C;
    int s0 = row_start[d], s1 = row_start[d + 1];
    float acc = 0.f;
    for (int s = s0; s < s1; ++s) {
        acc += alpha[(size_t)s * H + hd] * h[(size_t)slot_src[s] * HC + c];
    }
    acc += bias[c];
    if (ACT == 1) acc = (acc > 0.f) ? acc : (expf(acc) - 1.f);  // elu
    else          acc = fmaxf(acc, 0.f);
    out[(size_t)d * HC + c] = acc;
}

extern "C" void kernel_launch(void* const* d_in, const int* in_sizes, int n_in,
                              void* d_out, int out_size, void* d_ws, size_t ws_size,
                              hipStream_t stream) {
    const float* node      = (const float*)d_in[0];
    const int*   esrc      = (const int*)d_in[1];          // edge_index[0]
    const int*   edst      = ((const int*)d_in[1]) + EE;   // edge_index[1]
    const float* W1        = (const float*)d_in[2];
    const float* att_src1  = (const float*)d_in[3];
    const float* att_dst1  = (const float*)d_in[4];
    const float* b1        = (const float*)d_in[5];
    const float* W2        = (const float*)d_in[6];
    const float* att_src2  = (const float*)d_in[7];
    const float* att_dst2  = (const float*)d_in[8];
    const float* b2        = (const float*)d_in[9];
    const float* fc_w      = (const float*)d_in[10];
    const float* fc_b      = (const float*)d_in[11];
    float* out = (float*)d_out;

    // workspace layout
    float* h1    = (float*)d_ws;                 // [NN*HC1] ; reused as h2 [NN*HC2]
    float* x2    = h1 + (size_t)NN * HC1;        // [NN*HC1] ; reused as out2 [NN*HC2]
    float* alpha = x2 + (size_t)NN * HC1;        // [ETOT*H1] ; reused layer2 [ETOT]
    float* a_s1  = alpha + (size_t)ETOT * H1;    // [NN*H1]
    float* a_d1  = a_s1 + NN * H1;               // [NN*H1]
    float* a_s2  = a_d1 + NN * H1;               // [NN]
    float* a_d2  = a_s2 + NN;                    // [NN]
    int* deg       = (int*)(a_d2 + NN);          // [NN]
    int* cursor    = deg + NN;                   // [NN]
    int* row_start = cursor + NN;                // [NN+1]
    int* slot_src  = row_start + NN + 8;         // [ETOT]

    // ---- CSR build (shared by both layers) ----
    hipMemsetAsync(deg, 0, 2 * NN * sizeof(int), stream);  // deg + cursor
    hist_kernel<<<(ETOT + 255) / 256, 256, 0, stream>>>(edst, deg);
    scan_kernel<<<1, 1024, 0, stream>>>(deg, row_start);
    fill_kernel<<<(ETOT + 255) / 256, 256, 0, stream>>>(esrc, edst, row_start, cursor, slot_src);

    dim3 blk(16, 16);

    // ---- layer 1 ----
    // h1 = node @ W1
    gemm_f32<0><<<dim3(HC1 / 64, (NN + 63) / 64), blk, 0, stream>>>(node, W1, nullptr, h1, NN, HC1, F_IN);
    att_logits<<<NN * H1, 64, 0, stream>>>(h1, att_src1, att_dst1, a_s1, a_d1, H1, C1);
    att_alpha<<<NN, 64, 0, stream>>>(row_start, slot_src, a_s1, a_d1, alpha, H1);
    gat_scatter<1><<<dim3(NN, HC1 / 256), 256, 0, stream>>>(row_start, slot_src, alpha, h1, b1, x2, HC1, C1, H1);

    // ---- layer 2 ----
    float* h2 = h1;  // reuse
    gemm_f32<0><<<dim3(HC2 / 64, (NN + 63) / 64), blk, 0, stream>>>(x2, W2, nullptr, h2, NN, HC2, HC1);
    att_logits<<<NN * H2, 64, 0, stream>>>(h2, att_src2, att_dst2, a_s2, a_d2, H2, C2);
    att_alpha<<<NN, 64, 0, stream>>>(row_start, slot_src, a_s2, a_d2, alpha, H2);
    float* out2 = x2;  // reuse
    gat_scatter<2><<<dim3(NN, HC2 / 256), 256, 0, stream>>>(row_start, slot_src, alpha, h2, b2, out2, HC2, C2, H2);

    // ---- fc: out = relu(out2 @ fc_w + fc_b) ----
    gemm_f32<1><<<dim3(OUT_DIM / 64, (NN + 63) / 64), blk, 0, stream>>>(out2, fc_w, fc_b, out, NN, OUT_DIM, OUT_DIM);
}

// Round 2
// 334.312 us; speedup vs baseline: 4.6806x; 4.6806x over previous
//
#include <hip/hip_runtime.h>
#include <hip/hip_bf16.h>
#include <cstddef>
#include <cstdint>

// Problem constants
#define NN 10000
#define EE 160000
#define ETOT (EE + NN)
#define F_IN 128
#define H1 10
#define C1 128
#define HC1 1280
#define H2 1
#define C2 1024
#define HC2 1024
#define OUT_DIM 1024

typedef __attribute__((ext_vector_type(4))) float f32x4;
typedef __attribute__((ext_vector_type(8))) short s16x8;
typedef unsigned int u32;
typedef unsigned short u16;

__device__ __forceinline__ float bf2f(u16 v) {
    union { u32 u; float f; } x; x.u = ((u32)v) << 16; return x.f;
}
__device__ __forceinline__ u16 f2bf(float f) {
    union { float f; u32 u; } x; x.f = f;
    u32 u = x.u;
    u32 r = (u + 0x7fffu + ((u >> 16) & 1u)) >> 16;   // RNE
    return (u16)r;
}

__device__ __forceinline__ void gld16(const void* g, void* l) {
    __builtin_amdgcn_global_load_lds((const __attribute__((address_space(1))) u32*)g,
                                     (__attribute__((address_space(3))) u32*)l, 16, 0, 0);
}

// ---------------- conversions ----------------
__global__ void f32_to_bf16_kernel(const float* __restrict__ in, u16* __restrict__ out, int n) {
    int i = blockIdx.x * 256 + threadIdx.x;
    if (i < n) out[i] = f2bf(in[i]);
}

// in: [K][N] row-major f32; out: [N][K] bf16
__global__ void transpose_bf16_kernel(const float* __restrict__ in, u16* __restrict__ out,
                                      int K, int N) {
    int n = blockIdx.x * 16 + threadIdx.x;
    int k = blockIdx.y * 16 + threadIdx.y;
    if (n < N && k < K) out[(size_t)n * K + k] = f2bf(in[(size_t)k * N + n]);
}

// ---------------- CSR build ----------------
__global__ void hist_kernel(const int* __restrict__ edst, int* __restrict__ deg) {
    int e = blockIdx.x * 256 + threadIdx.x;
    if (e >= ETOT) return;
    int d = (e < EE) ? edst[e] : (e - EE);
    atomicAdd(&deg[d], 1);
}

__global__ void scan_kernel(const int* __restrict__ deg, int* __restrict__ row_start) {
    __shared__ int buf[1024];
    int carry = 0;
    for (int base = 0; base < NN; base += 1024) {
        int i = base + threadIdx.x;
        int v = (i < NN) ? deg[i] : 0;
        buf[threadIdx.x] = v;
        __syncthreads();
        for (int off = 1; off < 1024; off <<= 1) {
            int t = (threadIdx.x >= off) ? buf[threadIdx.x - off] : 0;
            __syncthreads();
            buf[threadIdx.x] += t;
            __syncthreads();
        }
        int incl = buf[threadIdx.x];
        if (i < NN) row_start[i] = carry + incl - v;   // exclusive
        carry += buf[1023];
        __syncthreads();
    }
    if (threadIdx.x == 0) row_start[NN] = carry;
}

__global__ void fill_kernel(const int* __restrict__ esrc, const int* __restrict__ edst,
                            const int* __restrict__ row_start, int* __restrict__ cursor,
                            int* __restrict__ slot_src) {
    int e = blockIdx.x * 256 + threadIdx.x;
    if (e >= ETOT) return;
    int s, d;
    if (e < EE) { s = esrc[e]; d = edst[e]; }
    else        { s = d = e - EE; }
    int pos = atomicAdd(&cursor[d], 1);
    slot_src[row_start[d] + pos] = s;
}

// ---------------- bf16 MFMA GEMM: C = A[MxK] * Bt[NxK]^T ----------------
// 128x128 tile, 4 waves (2x2), 16x16x32 MFMA, BK=32, global_load_lds staging.
// BIAS_RELU==0: store bf16 (no bias/act). BIAS_RELU==1: +bias, relu, store f32.
template<int BIAS_RELU>
__global__ __launch_bounds__(256, 2)
void gemm_bf16(const u16* __restrict__ A, const u16* __restrict__ Bt,
               const float* __restrict__ bias, void* __restrict__ Cout,
               int M, int N, int K) {
    __shared__ u16 Als[128 * 32];
    __shared__ u16 Bls[128 * 32];
    const int tid  = threadIdx.x;
    const int wave = tid >> 6;
    const int lane = tid & 63;
    const int bm = blockIdx.y * 128;
    const int bn = blockIdx.x * 128;
    const int wr = wave >> 1, wc = wave & 1;   // 2x2 waves, each 64x64
    const int lr = lane & 15;                  // fragment row/col within 16
    const int kc = lane >> 4;                  // k-chunk 0..3

    f32x4 acc[4][4] = {};

    // staging geometry: per 4096B chunk, thread t covers byte t*16
    const int srow = tid >> 2;             // 0..63
    const int scol = (tid & 3) * 8;        // element col in [0,32)
    int arow0 = bm + srow;       if (arow0 >= M) arow0 = M - 1;   // clamp: pad rows never stored
    int arow1 = bm + 64 + srow;  if (arow1 >= M) arow1 = M - 1;
    const int brow0 = bn + srow;           // N is a multiple of 128
    const int brow1 = bn + 64 + srow;

    for (int k0 = 0; k0 < K; k0 += 32) {
        gld16(A  + (size_t)arow0 * K + k0 + scol, &Als[(size_t)wave * 512]);
        gld16(A  + (size_t)arow1 * K + k0 + scol, &Als[2048 + (size_t)wave * 512]);
        gld16(Bt + (size_t)brow0 * K + k0 + scol, &Bls[(size_t)wave * 512]);
        gld16(Bt + (size_t)brow1 * K + k0 + scol, &Bls[2048 + (size_t)wave * 512]);
        __syncthreads();

        s16x8 af[4], bg[4];
#pragma unroll
        for (int i = 0; i < 4; ++i)
            af[i] = *(const s16x8*)&Als[(wr * 64 + i * 16 + lr) * 32 + kc * 8];
#pragma unroll
        for (int j = 0; j < 4; ++j)
            bg[j] = *(const s16x8*)&Bls[(wc * 64 + j * 16 + lr) * 32 + kc * 8];
#pragma unroll
        for (int i = 0; i < 4; ++i)
#pragma unroll
            for (int j = 0; j < 4; ++j)
                acc[i][j] = __builtin_amdgcn_mfma_f32_16x16x32_bf16(af[i], bg[j], acc[i][j], 0, 0, 0);
        __syncthreads();
    }

    // C/D layout: col = lane&15, row = (lane>>4)*4 + reg
#pragma unroll
    for (int i = 0; i < 4; ++i) {
#pragma unroll
        for (int r = 0; r < 4; ++r) {
            int m = bm + wr * 64 + i * 16 + kc * 4 + r;
            if (m >= M) continue;
#pragma unroll
            for (int j = 0; j < 4; ++j) {
                int n = bn + wc * 64 + j * 16 + lr;
                float v = acc[i][j][r];
                if (BIAS_RELU) {
                    v += bias[n];
                    v = fmaxf(v, 0.f);
                    ((float*)Cout)[(size_t)m * N + n] = v;
                } else {
                    ((u16*)Cout)[(size_t)m * N + n] = f2bf(v);
                }
            }
        }
    }
}

// ---------------- attention logits from bf16 h ----------------
__global__ void att_logits_bf16(const u16* __restrict__ h, const float* __restrict__ att_s,
                                const float* __restrict__ att_d, float* __restrict__ a_s,
                                float* __restrict__ a_d, int H, int C) {
    int nh = blockIdx.x;
    int n = nh / H, hd = nh % H;
    int lane = threadIdx.x;
    const u16* row = h + (size_t)n * H * C + (size_t)hd * C;
    float ps = 0.f, pd = 0.f;
    for (int c = lane; c < C; c += 64) {
        float v = bf2f(row[c]);
        ps += v * att_s[hd * C + c];
        pd += v * att_d[hd * C + c];
    }
    for (int off = 32; off; off >>= 1) {
        ps += __shfl_down(ps, off);
        pd += __shfl_down(pd, off);
    }
    if (lane == 0) {
        a_s[n * H + hd] = ps;
        a_d[n * H + hd] = pd;
    }
}

// ---------------- per-dst softmax over in-edges (CSR) ----------------
__global__ void att_alpha(const int* __restrict__ row_start, const int* __restrict__ slot_src,
                          const float* __restrict__ a_s, const float* __restrict__ a_d,
                          float* __restrict__ alpha, int H) {
    int d = blockIdx.x;
    int lane = threadIdx.x;
    int s0 = row_start[d], s1 = row_start[d + 1];
    for (int hd = 0; hd < H; ++hd) {
        float ad = a_d[d * H + hd];
        float sum = 0.f;
        for (int s = s0 + lane; s < s1; s += 64) {
            float e = a_s[slot_src[s] * H + hd] + ad;
            e = (e > 0.f) ? e : 0.2f * e;          // leaky_relu 0.2
            float ex = expf(e);                     // logits are small by construction
            alpha[(size_t)s * H + hd] = ex;
            sum += ex;
        }
        for (int off = 32; off; off >>= 1) sum += __shfl_down(sum, off);
        sum = __shfl(sum, 0);
        float inv = 1.f / (sum + 1e-16f);
        for (int s = s0 + lane; s < s1; s += 64) alpha[(size_t)s * H + hd] *= inv;
    }
}

// ---------------- scatter: out[d,c] = act( sum_e alpha[e,h] * h[src,c] + bias[c] ), bf16 io ----
// ACT: 1 = elu, 2 = relu. block = 64 threads, each handles 4 contiguous channels.
template<int ACT>
__global__ void gat_scatter_bf16(const int* __restrict__ row_start, const int* __restrict__ slot_src,
                                 const float* __restrict__ alpha, const u16* __restrict__ h,
                                 const float* __restrict__ bias, u16* __restrict__ out,
                                 int HC, int C, int H) {
    int d = blockIdx.x;
    int c0 = (blockIdx.y * 64 + threadIdx.x) * 4;
    int hd = c0 / C;
    int s0 = row_start[d], s1 = row_start[d + 1];
    float a0 = 0.f, a1 = 0.f, a2 = 0.f, a3 = 0.f;
    for (int s = s0; s < s1; ++s) {
        int src = slot_src[s];
        float a = alpha[(size_t)s * H + hd];
        ushort4 v = *(const ushort4*)(h + (size_t)src * HC + c0);
        a0 += a * bf2f(v.x);
        a1 += a * bf2f(v.y);
        a2 += a * bf2f(v.z);
        a3 += a * bf2f(v.w);
    }
    a0 += bias[c0];
    a1 += bias[c0 + 1];
    a2 += bias[c0 + 2];
    a3 += bias[c0 + 3];
    if (ACT == 1) {
        a0 = (a0 > 0.f) ? a0 : (expf(a0) - 1.f);
        a1 = (a1 > 0.f) ? a1 : (expf(a1) - 1.f);
        a2 = (a2 > 0.f) ? a2 : (expf(a2) - 1.f);
        a3 = (a3 > 0.f) ? a3 : (expf(a3) - 1.f);
    } else {
        a0 = fmaxf(a0, 0.f); a1 = fmaxf(a1, 0.f);
        a2 = fmaxf(a2, 0.f); a3 = fmaxf(a3, 0.f);
    }
    ushort4 o;
    o.x = f2bf(a0); o.y = f2bf(a1); o.z = f2bf(a2); o.w = f2bf(a3);
    *(ushort4*)(out + (size_t)d * HC + c0) = o;
}

extern "C" void kernel_launch(void* const* d_in, const int* in_sizes, int n_in,
                              void* d_out, int out_size, void* d_ws, size_t ws_size,
                              hipStream_t stream) {
    const float* node      = (const float*)d_in[0];
    const int*   esrc      = (const int*)d_in[1];          // edge_index[0]
    const int*   edst      = ((const int*)d_in[1]) + EE;   // edge_index[1]
    const float* W1        = (const float*)d_in[2];
    const float* att_src1  = (const float*)d_in[3];
    const float* att_dst1  = (const float*)d_in[4];
    const float* b1        = (const float*)d_in[5];
    const float* W2        = (const float*)d_in[6];
    const float* att_src2  = (const float*)d_in[7];
    const float* att_dst2  = (const float*)d_in[8];
    const float* b2        = (const float*)d_in[9];
    const float* fc_w      = (const float*)d_in[10];
    const float* fc_b      = (const float*)d_in[11];
    float* out = (float*)d_out;

    // ---- workspace layout (bf16 first, then f32, then ints) ----
    u16* bufA  = (u16*)d_ws;                        // [NN*HC1]  h1b, later h2b
    u16* bufB  = bufA + (size_t)NN * HC1;           // [NN*HC1]  x2b, later out2b
    u16* nodeb = bufB + (size_t)NN * HC1;           // [NN*F_IN]
    u16* w1t   = nodeb + (size_t)NN * F_IN;         // [HC1*F_IN]
    u16* w2t   = w1t + (size_t)HC1 * F_IN;          // [HC2*HC1]
    u16* fcwt  = w2t + (size_t)HC2 * HC1;           // [OUT_DIM*OUT_DIM]
    float* alpha = (float*)(fcwt + (size_t)OUT_DIM * OUT_DIM);  // [ETOT*H1]
    float* a_s1  = alpha + (size_t)ETOT * H1;       // [NN*H1]
    float* a_d1  = a_s1 + (size_t)NN * H1;
    float* a_s2  = a_d1 + (size_t)NN * H1;          // [NN]
    float* a_d2  = a_s2 + NN;
    int* deg       = (int*)(a_d2 + NN);
    int* cursor    = deg + NN;
    int* row_start = cursor + NN;                   // [NN+1]
    int* slot_src  = row_start + NN + 8;            // [ETOT]

    // ---- conversions ----
    f32_to_bf16_kernel<<<(NN * F_IN + 255) / 256, 256, 0, stream>>>(node, nodeb, NN * F_IN);
    transpose_bf16_kernel<<<dim3(HC1 / 16, F_IN / 16), dim3(16, 16), 0, stream>>>(W1, w1t, F_IN, HC1);
    transpose_bf16_kernel<<<dim3(HC2 / 16, HC1 / 16), dim3(16, 16), 0, stream>>>(W2, w2t, HC1, HC2);
    transpose_bf16_kernel<<<dim3(OUT_DIM / 16, OUT_DIM / 16), dim3(16, 16), 0, stream>>>(fc_w, fcwt, OUT_DIM, OUT_DIM);

    // ---- CSR build ----
    hipMemsetAsync(deg, 0, 2 * NN * sizeof(int), stream);  // deg + cursor
    hist_kernel<<<(ETOT + 255) / 256, 256, 0, stream>>>(edst, deg);
    scan_kernel<<<1, 1024, 0, stream>>>(deg, row_start);
    fill_kernel<<<(ETOT + 255) / 256, 256, 0, stream>>>(esrc, edst, row_start, cursor, slot_src);

    // ---- layer 1 ----
    gemm_bf16<0><<<dim3(HC1 / 128, (NN + 127) / 128), 256, 0, stream>>>(nodeb, w1t, nullptr, bufA, NN, HC1, F_IN);
    att_logits_bf16<<<NN * H1, 64, 0, stream>>>(bufA, att_src1, att_dst1, a_s1, a_d1, H1, C1);
    att_alpha<<<NN, 64, 0, stream>>>(row_start, slot_src, a_s1, a_d1, alpha, H1);
    gat_scatter_bf16<1><<<dim3(NN, HC1 / 256), 64, 0, stream>>>(row_start, slot_src, alpha, bufA, b1, bufB, HC1, C1, H1);

    // ---- layer 2 ----
    gemm_bf16<0><<<dim3(HC2 / 128, (NN + 127) / 128), 256, 0, stream>>>(bufB, w2t, nullptr, bufA, NN, HC2, HC1);
    att_logits_bf16<<<NN * H2, 64, 0, stream>>>(bufA, att_src2, att_dst2, a_s2, a_d2, H2, C2);
    att_alpha<<<NN, 64, 0, stream>>>(row_start, slot_src, a_s2, a_d2, alpha, H2);
    gat_scatter_bf16<2><<<dim3(NN, HC2 / 256), 64, 0, stream>>>(row_start, slot_src, alpha, bufA, b2, bufB, HC2, C2, H2);

    // ---- fc: out = relu(out2 @ fc_w + fc_b), f32 out ----
    gemm_bf16<1><<<dim3(OUT_DIM / 128, (NN + 127) / 128), 256, 0, stream>>>(bufB, fcwt, fc_b, out, NN, OUT_DIM, OUT_DIM);
}